// Round 19
// baseline (36.817 us; speedup 1.0000x reference)
//
#include <hip/hip_runtime.h>

static constexpr int NSEQ = 512;
static constexpr int NB = 32;
static constexpr int LDS_BYTES = 140288;  // 131072 dm + 4096 A2 + 5120 B2pad

typedef _Float16 h2v __attribute__((ext_vector_type(2)));

// lane l <- lane (l-1)&63 : DPP wave rotate-right-by-1 (verified R5-R17).
// Must execute at full exec.
__device__ __forceinline__ float rotup1f(float v) {
  return __int_as_float(__builtin_amdgcn_update_dpp(
      0, __float_as_int(v), 0x13C, 0xf, 0xf, false));
}
__device__ __forceinline__ int rlanei(int v, int idx) {
  return __builtin_amdgcn_readlane(v, idx);
}
__device__ __forceinline__ h2v BCH(unsigned v) { return __builtin_bit_cast(h2v, v); }
__device__ __forceinline__ unsigned packh2s(float a, float b) {
  h2v v; v[0] = (_Float16)a; v[1] = (_Float16)b;
  return __builtin_bit_cast(unsigned, v);
}
#if __has_builtin(__builtin_amdgcn_fdot2)
#define DOT2(a, b, c) __builtin_amdgcn_fdot2((a), (b), (c), false)
#else
__device__ __forceinline__ float dot2f(h2v a, h2v b, float c) {
  return c + (float)a[0] * (float)b[0] + (float)a[1] * (float)b[1];
}
#define DOT2(a, b, c) dot2f((a), (b), (c))
#endif
// v_cvt_pk_bf16_f32: d = {hi: bf16(s1), lo: bf16(s0)}
__device__ __forceinline__ unsigned cvtpk_bf16(float lo, float hi) {
  unsigned r;
  asm("v_cvt_pk_bf16_f32 %0, %1, %2" : "=v"(r) : "v"(lo), "v"(hi));
  return r;
}

// R19 = R17 exactly (passed, 30.5us: full dmp zeroing — MANDATORY, ~13/64
// interior lanes have no stage-1 writer and must read 0; renorm cadence 28
// steps to target 2^60 — E drifts ~6 bits/step, 168 bits/group vs 186 bits
// of headroom) + fused combine via last-block pattern (R18's only sound cut).
__global__ __launch_bounds__(1024) void softdtw_fused(
    const float* __restrict__ x, const float* __restrict__ y,
    float* __restrict__ ws, unsigned* __restrict__ ctr,
    float* __restrict__ out)
{
  extern __shared__ unsigned char lds_raw[];
  unsigned* dmp = (unsigned*)lds_raw;                 // [512][64] u32 (row 511 scratch)
  uint2* A2  = (uint2*)(lds_raw + 131072);            // [512] f16x4
  uint2* B2p = (uint2*)(lds_raw + 135168);            // [640]; b[j] at index 64+j

  const int k = blockIdx.x;
  const int batch = k & (NB - 1);
  const int type = k >> 5;
  const float4* Aq = (const float4*)((type == 2 ? y : x) + (size_t)batch * NSEQ * 4);
  const float4* Bq = (const float4*)((type == 1 ? x : y) + (size_t)batch * NSEQ * 4);

  const int tid = threadIdx.x;
  const int l = tid & 63;
  const float SK1 = 0.8493216783f;      // sqrt(1/(2 ln2)); inputs prescaled
  const float K2 = 1.386294361119891f;  // gamma*ln2

  // ---- staging: zero FULL dm region; prescaled f16 a,b; inf pads ----
  {
    uint4* z = (uint4*)lds_raw;         // 8192 uint4 = 131072 B
    #pragma unroll
    for (int q = 0; q < 8; ++q) z[tid + q * 1024] = make_uint4(0u, 0u, 0u, 0u);
    int idx = tid & 511;
    const float4* src = (tid < 512) ? Aq : Bq;
    float4 v = src[idx];
    unsigned w01 = packh2s(v.x * SK1, v.y * SK1);
    unsigned w23 = packh2s(v.z * SK1, v.w * SK1);
    if (tid < 512) A2[idx] = make_uint2(w01, w23);
    else           B2p[64 + idx] = make_uint2(w01, w23);
    if (tid < 64)       B2p[tid] = make_uint2(0x7C007C00u, 0x7C007C00u);
    else if (tid < 128) B2p[512 + tid] = make_uint2(0x7C007C00u, 0x7C007C00u);
  }
  __syncthreads();

  // ---- stage 1 (i-major, R17-verified): wave (bi,h); i = 64*bi + l ----
  {
    const int wv = tid >> 6;
    const int bi = wv >> 1;
    const int h  = wv & 1;
    const int i  = bi * 64 + l;
    uint2 aw = A2[i];
    h2v a01 = BCH(aw.x), a23 = BCH(aw.y);

    if (h == 0) {
      uint2 bw = B2p[64 + i - 50];            // j = i-50
      h2v d01 = a01 - BCH(bw.x), d23 = a23 - BCH(bw.y);
      float dvv = DOT2(d01, d01, DOT2(d23, d23, 0.0f));
      unsigned w = cvtpk_bf16(0.0f, __builtin_exp2f(-dvv));
      unsigned p = (unsigned)(i - 26);
      if (p > 510u) p = 511u;                 // scratch row (never read)
      dmp[p * 64 + l] = w;
    }
    const int q0 = h ? 0 : -25;
    #pragma unroll 5
    for (int n = 0; n < 25; ++n) {
      int q = q0 + n;
      const uint2* bp = &B2p[64 + i + 2 * q + 1];
      uint2 blo = bp[0];
      uint2 bhi = bp[1];
      h2v e01 = a01 - BCH(blo.x), e23 = a23 - BCH(blo.y);
      float dvl = DOT2(e01, e01, DOT2(e23, e23, 0.0f));
      h2v f01 = a01 - BCH(bhi.x), f23 = a23 - BCH(bhi.y);
      float dvh = DOT2(f01, f01, DOT2(f23, f23, 0.0f));
      unsigned w = cvtpk_bf16(__builtin_exp2f(-dvl), __builtin_exp2f(-dvh));
      unsigned p = (unsigned)(i + q);
      if (p > 510u) p = 511u;
      dmp[p * 64 + l] = w;
    }
  }
  __syncthreads();
  if (tid >= 64) return;

  // ---- stage 2: single-wave DP, rotated state (R17-verified) ----
  const unsigned* wp = dmp + l;
  unsigned c0 = wp[0],   c1 = wp[64],  c2 = wp[128], c3 = wp[192],
           c4 = wp[256], c5 = wp[320], c6 = wp[384], c7 = wp[448],
           c8 = wp[512], c9 = wp[576], c10 = wp[640], c11 = wp[704],
           c12 = wp[768], c13 = wp[832];
  unsigned n0, n1, n2, n3, n4, n5, n6, n7, n8, n9, n10, n11, n12, n13;
  int S = 0;

  float E1, r1, r2 = 0.0f;
  {
    uint2 aw = A2[0];
    uint2 bw = B2p[64];
    h2v d01 = BCH(aw.x) - BCH(bw.x);
    h2v d23 = BCH(aw.y) - BCH(bw.y);
    float dv00 = DOT2(d01, d01, DOT2(d23, d23, 0.0f));
    E1 = (l == 0) ? __builtin_exp2f(-dv00) : 0.0f;
  }
  r1 = rotup1f(E1);

#define MAC(W)                                                                 \
  {                                                                            \
    float dlo_ = __int_as_float((W) << 16);                                    \
    float dhi_ = __int_as_float((W) & 0xFFFF0000u);                            \
    float sA_ = E1 + r1; sA_ += r2;                                            \
    float eA_ = sA_ * dlo_;                                                    \
    float rA_ = rotup1f(eA_);                                                  \
    float sB_ = eA_ + rA_; sB_ += r1;                                          \
    float eB_ = sB_ * dhi_;                                                    \
    float rB_ = rotup1f(eB_);                                                  \
    E1 = eB_; r2 = rA_; r1 = rB_;                                              \
  }
#define RENORM                                                                 \
  {                                                                            \
    float mx_ = fmaxf(E1, r2);                                                 \
    mx_ = fmaxf(mx_, __int_as_float(__builtin_amdgcn_update_dpp(               \
        0, __float_as_int(mx_), 0x111, 0xf, 0xf, false)));                     \
    mx_ = fmaxf(mx_, __int_as_float(__builtin_amdgcn_update_dpp(               \
        0, __float_as_int(mx_), 0x112, 0xf, 0xf, false)));                     \
    mx_ = fmaxf(mx_, __int_as_float(__builtin_amdgcn_update_dpp(               \
        0, __float_as_int(mx_), 0x114, 0xf, 0xf, false)));                     \
    mx_ = fmaxf(mx_, __int_as_float(__builtin_amdgcn_update_dpp(               \
        0, __float_as_int(mx_), 0x118, 0xf, 0xf, false)));                     \
    mx_ = fmaxf(mx_, __int_as_float(__builtin_amdgcn_update_dpp(               \
        0, __float_as_int(mx_), 0x142, 0xf, 0xf, false)));                     \
    mx_ = fmaxf(mx_, __int_as_float(__builtin_amdgcn_update_dpp(               \
        0, __float_as_int(mx_), 0x143, 0xf, 0xf, false)));                     \
    int c_ = 187 - ((__float_as_int(mx_) >> 23) & 0xFF);                       \
    c_ = rlanei(c_, 63);                                                       \
    E1 = __builtin_ldexpf(E1, c_);                                             \
    r1 = __builtin_ldexpf(r1, c_);                                             \
    r2 = __builtin_ldexpf(r2, c_);                                             \
    S += c_;                                                                   \
  }
#define GROUP(C0,C1,C2,C3,C4,C5,C6,C7,C8,C9,C10,C11,C12,C13,                   \
              N0,N1,N2,N3,N4,N5,N6,N7,N8,N9,N10,N11,N12,N13)                   \
  {                                                                            \
    N0 = wp[896];  N1 = wp[960];  N2 = wp[1024]; N3 = wp[1088];                \
    N4 = wp[1152]; N5 = wp[1216]; N6 = wp[1280]; N7 = wp[1344];                \
    N8 = wp[1408]; N9 = wp[1472]; N10 = wp[1536]; N11 = wp[1600];              \
    N12 = wp[1664]; N13 = wp[1728];                                            \
    MAC(C0) MAC(C1) MAC(C2) MAC(C3) MAC(C4) MAC(C5) MAC(C6)                    \
    MAC(C7) MAC(C8) MAC(C9) MAC(C10) MAC(C11) MAC(C12) MAC(C13)                \
    RENORM                                                                     \
    wp += 896;                                                                 \
  }

  // 36 groups x 14 words + 7-word tail = 511 pairs = diagonals 1..1022.
  #pragma clang loop unroll(disable)
  for (int it = 0; it < 18; ++it) {
    GROUP(c0,c1,c2,c3,c4,c5,c6,c7,c8,c9,c10,c11,c12,c13,
          n0,n1,n2,n3,n4,n5,n6,n7,n8,n9,n10,n11,n12,n13)
    GROUP(n0,n1,n2,n3,n4,n5,n6,n7,n8,n9,n10,n11,n12,n13,
          c0,c1,c2,c3,c4,c5,c6,c7,c8,c9,c10,c11,c12,c13)
  }
  // tail: words 504..510
  MAC(c0) MAC(c1) MAC(c2) MAC(c3) MAC(c4) MAC(c5) MAC(c6)

#undef GROUP
#undef RENORM
#undef MAC

  // R[511,511] on lane 63; stored E = true * 2^S.
  if (l == 63) {
    ws[k] = -K2 * (__builtin_log2f(E1) - (float)S);
  }

  // ---- fused combine: last block to finish writes the 32 outputs ----
  __threadfence();                         // release ws[k] device-wide
  unsigned old = 0;
  if (l == 0) old = atomicAdd(ctr, 1u);    // device(agent)-scope
  old = (unsigned)rlanei((int)old, 0);
  if (old == 95u) {
    __threadfence();                       // acquire
    if (l < NB) {
      float a = __hip_atomic_load(&ws[l],          __ATOMIC_RELAXED,
                                  __HIP_MEMORY_SCOPE_AGENT);
      float b = __hip_atomic_load(&ws[NB + l],     __ATOMIC_RELAXED,
                                  __HIP_MEMORY_SCOPE_AGENT);
      float c = __hip_atomic_load(&ws[2 * NB + l], __ATOMIC_RELAXED,
                                  __HIP_MEMORY_SCOPE_AGENT);
      out[l] = a - 0.5f * (b + c);
    }
  }
}

extern "C" void kernel_launch(void* const* d_in, const int* in_sizes, int n_in,
                              void* d_out, int out_size, void* d_ws, size_t ws_size,
                              hipStream_t stream) {
  const float* x = (const float*)d_in[0];
  const float* y = (const float*)d_in[1];
  float* ws = (float*)d_ws;
  unsigned* ctr = (unsigned*)((char*)d_ws + 384);   // after 96 ws floats
  float* out = (float*)d_out;
  // >64KB dynamic LDS opt-in (not a stream op; capture-safe, idempotent).
  hipFuncSetAttribute((const void*)softdtw_fused,
                      hipFuncAttributeMaxDynamicSharedMemorySize, LDS_BYTES);
  hipMemsetAsync(ctr, 0, 4, stream);                // reset last-block counter
  softdtw_fused<<<3 * NB, 1024, LDS_BYTES, stream>>>(x, y, ws, ctr, out);
}

// Round 20
// 28.756 us; speedup vs baseline: 1.2803x; 1.2803x over previous
//
#include <hip/hip_runtime.h>

static constexpr int NSEQ = 512;
static constexpr int NB = 32;
static constexpr int LDS_BYTES = 140288;  // 131072 dm + 4096 A2 + 5120 B2pad

typedef _Float16 h2v __attribute__((ext_vector_type(2)));

// lane l <- lane (l-1)&63 : DPP wave rotate-right-by-1 (verified R5-R17).
// Must execute at full exec.
__device__ __forceinline__ float rotup1f(float v) {
  return __int_as_float(__builtin_amdgcn_update_dpp(
      0, __float_as_int(v), 0x13C, 0xf, 0xf, false));
}
__device__ __forceinline__ int rlanei(int v, int idx) {
  return __builtin_amdgcn_readlane(v, idx);
}
__device__ __forceinline__ h2v BCH(unsigned v) { return __builtin_bit_cast(h2v, v); }
__device__ __forceinline__ unsigned packh2s(float a, float b) {
  h2v v; v[0] = (_Float16)a; v[1] = (_Float16)b;
  return __builtin_bit_cast(unsigned, v);
}
#if __has_builtin(__builtin_amdgcn_fdot2)
#define DOT2(a, b, c) __builtin_amdgcn_fdot2((a), (b), (c), false)
#else
__device__ __forceinline__ float dot2f(h2v a, h2v b, float c) {
  return c + (float)a[0] * (float)b[0] + (float)a[1] * (float)b[1];
}
#define DOT2(a, b, c) dot2f((a), (b), (c))
#endif
// v_cvt_pk_bf16_f32: d = {hi: bf16(s1), lo: bf16(s0)}
__device__ __forceinline__ unsigned cvtpk_bf16(float lo, float hi) {
  unsigned r;
  asm("v_cvt_pk_bf16_f32 %0, %1, %2" : "=v"(r) : "v"(lo), "v"(hi));
  return r;
}

// R20 = R17 (verified 30.5us; combine kernel restored after R19's fused
// regression) + stage-1/stage-2 OVERLAP: pairs <=229 are written only by
// the 8 waves with bi<=3, so the consumer starts the DP after an LDS
// counter says those 8 are done (ds ops in-order per wave => counter==8
// implies their dm stores are visible), runs groups 0..13 (words<=195,
// prefetch<=209), then waits for the second counter before the rest.
// Second-half production (~2.5us) hides under the DP prefix (~7us).
__global__ __launch_bounds__(1024) void softdtw_fused(
    const float* __restrict__ x, const float* __restrict__ y,
    float* __restrict__ ws)
{
  extern __shared__ unsigned char lds_raw[];
  unsigned* dmp = (unsigned*)lds_raw;                 // [512][64] u32 (row 511 scratch)
  uint2* A2  = (uint2*)(lds_raw + 131072);            // [512] f16x4
  uint2* B2p = (uint2*)(lds_raw + 135168);            // [640]; b[j] at index 64+j
  unsigned* cnt = (unsigned*)(lds_raw + 135168 + 96); // B2p[12]: {cnt1, cnt2} (never read as data)

  const int k = blockIdx.x;
  const int batch = k & (NB - 1);
  const int type = k >> 5;
  const float4* Aq = (const float4*)((type == 2 ? y : x) + (size_t)batch * NSEQ * 4);
  const float4* Bq = (const float4*)((type == 1 ? x : y) + (size_t)batch * NSEQ * 4);

  const int tid = threadIdx.x;
  const int l = tid & 63;
  const float SK1 = 0.8493216783f;      // sqrt(1/(2 ln2)); inputs prescaled
  const float K2 = 1.386294361119891f;  // gamma*ln2

  // ---- staging: zero FULL dm region; prescaled f16 a,b; inf pads; counters ----
  {
    uint4* z = (uint4*)lds_raw;         // 8192 uint4 = 131072 B
    #pragma unroll
    for (int q = 0; q < 8; ++q) z[tid + q * 1024] = make_uint4(0u, 0u, 0u, 0u);
    int idx = tid & 511;
    const float4* src = (tid < 512) ? Aq : Bq;
    float4 v = src[idx];
    unsigned w01 = packh2s(v.x * SK1, v.y * SK1);
    unsigned w23 = packh2s(v.z * SK1, v.w * SK1);
    if (tid < 512) A2[idx] = make_uint2(w01, w23);
    else           B2p[64 + idx] = make_uint2(w01, w23);
    if (tid < 64) {
      // index 12 doubles as the two progress counters (B2p reads start at 14)
      B2p[tid] = (tid == 12) ? make_uint2(0u, 0u)
                             : make_uint2(0x7C007C00u, 0x7C007C00u);
    } else if (tid < 128) {
      B2p[512 + tid] = make_uint2(0x7C007C00u, 0x7C007C00u);
    }
  }
  __syncthreads();   // the ONLY workgroup barrier

  // ---- stage 1 (i-major, R17-verified): wave (bi,h); i = 64*bi + l ----
  {
    const int wv = tid >> 6;
    const int bi = wv >> 1;
    const int h  = wv & 1;
    const int i  = bi * 64 + l;
    uint2 aw = A2[i];
    h2v a01 = BCH(aw.x), a23 = BCH(aw.y);

    if (h == 0) {
      uint2 bw = B2p[64 + i - 50];            // j = i-50
      h2v d01 = a01 - BCH(bw.x), d23 = a23 - BCH(bw.y);
      float dvv = DOT2(d01, d01, DOT2(d23, d23, 0.0f));
      unsigned w = cvtpk_bf16(0.0f, __builtin_exp2f(-dvv));
      unsigned p = (unsigned)(i - 26);
      if (p > 510u) p = 511u;                 // scratch row (never read)
      dmp[p * 64 + l] = w;
    }
    const int q0 = h ? 0 : -25;
    #pragma unroll 5
    for (int n = 0; n < 25; ++n) {
      int q = q0 + n;
      const uint2* bp = &B2p[64 + i + 2 * q + 1];
      uint2 blo = bp[0];
      uint2 bhi = bp[1];
      h2v e01 = a01 - BCH(blo.x), e23 = a23 - BCH(blo.y);
      float dvl = DOT2(e01, e01, DOT2(e23, e23, 0.0f));
      h2v f01 = a01 - BCH(bhi.x), f23 = a23 - BCH(bhi.y);
      float dvh = DOT2(f01, f01, DOT2(f23, f23, 0.0f));
      unsigned w = cvtpk_bf16(__builtin_exp2f(-dvl), __builtin_exp2f(-dvh));
      unsigned p = (unsigned)(i + q);
      if (p > 510u) p = 511u;
      dmp[p * 64 + l] = w;
    }
    // progress: first-half waves (bi<=3, pairs<=229+margin) bump cnt[0],
    // second-half bump cnt[1]. DS queue is in-order per wave, so the add
    // is visible only after this wave's dm stores.
    if (l == 0) atomicAdd(&cnt[(bi <= 3) ? 0 : 1], 1u);
  }
  if (tid >= 64) return;

  volatile unsigned* vcnt = (volatile unsigned*)cnt;
  while (vcnt[0] < 8u) { }   // pairs 0..229 ready

  // ---- stage 2: single-wave DP, rotated state (R17-verified) ----
  const unsigned* wp = dmp + l;
  unsigned c0 = wp[0],   c1 = wp[64],  c2 = wp[128], c3 = wp[192],
           c4 = wp[256], c5 = wp[320], c6 = wp[384], c7 = wp[448],
           c8 = wp[512], c9 = wp[576], c10 = wp[640], c11 = wp[704],
           c12 = wp[768], c13 = wp[832];
  unsigned n0, n1, n2, n3, n4, n5, n6, n7, n8, n9, n10, n11, n12, n13;
  int S = 0;

  float E1, r1, r2 = 0.0f;
  {
    uint2 aw = A2[0];
    uint2 bw = B2p[64];
    h2v d01 = BCH(aw.x) - BCH(bw.x);
    h2v d23 = BCH(aw.y) - BCH(bw.y);
    float dv00 = DOT2(d01, d01, DOT2(d23, d23, 0.0f));
    E1 = (l == 0) ? __builtin_exp2f(-dv00) : 0.0f;
  }
  r1 = rotup1f(E1);

#define MAC(W)                                                                 \
  {                                                                            \
    float dlo_ = __int_as_float((W) << 16);                                    \
    float dhi_ = __int_as_float((W) & 0xFFFF0000u);                            \
    float sA_ = E1 + r1; sA_ += r2;                                            \
    float eA_ = sA_ * dlo_;                                                    \
    float rA_ = rotup1f(eA_);                                                  \
    float sB_ = eA_ + rA_; sB_ += r1;                                          \
    float eB_ = sB_ * dhi_;                                                    \
    float rB_ = rotup1f(eB_);                                                  \
    E1 = eB_; r2 = rA_; r1 = rB_;                                              \
  }
#define RENORM                                                                 \
  {                                                                            \
    float mx_ = fmaxf(E1, r2);                                                 \
    mx_ = fmaxf(mx_, __int_as_float(__builtin_amdgcn_update_dpp(               \
        0, __float_as_int(mx_), 0x111, 0xf, 0xf, false)));                     \
    mx_ = fmaxf(mx_, __int_as_float(__builtin_amdgcn_update_dpp(               \
        0, __float_as_int(mx_), 0x112, 0xf, 0xf, false)));                     \
    mx_ = fmaxf(mx_, __int_as_float(__builtin_amdgcn_update_dpp(               \
        0, __float_as_int(mx_), 0x114, 0xf, 0xf, false)));                     \
    mx_ = fmaxf(mx_, __int_as_float(__builtin_amdgcn_update_dpp(               \
        0, __float_as_int(mx_), 0x118, 0xf, 0xf, false)));                     \
    mx_ = fmaxf(mx_, __int_as_float(__builtin_amdgcn_update_dpp(               \
        0, __float_as_int(mx_), 0x142, 0xf, 0xf, false)));                     \
    mx_ = fmaxf(mx_, __int_as_float(__builtin_amdgcn_update_dpp(               \
        0, __float_as_int(mx_), 0x143, 0xf, 0xf, false)));                     \
    int c_ = 187 - ((__float_as_int(mx_) >> 23) & 0xFF);                       \
    c_ = rlanei(c_, 63);                                                       \
    E1 = __builtin_ldexpf(E1, c_);                                             \
    r1 = __builtin_ldexpf(r1, c_);                                             \
    r2 = __builtin_ldexpf(r2, c_);                                             \
    S += c_;                                                                   \
  }
#define GROUP(C0,C1,C2,C3,C4,C5,C6,C7,C8,C9,C10,C11,C12,C13,                   \
              N0,N1,N2,N3,N4,N5,N6,N7,N8,N9,N10,N11,N12,N13)                   \
  {                                                                            \
    N0 = wp[896];  N1 = wp[960];  N2 = wp[1024]; N3 = wp[1088];                \
    N4 = wp[1152]; N5 = wp[1216]; N6 = wp[1280]; N7 = wp[1344];                \
    N8 = wp[1408]; N9 = wp[1472]; N10 = wp[1536]; N11 = wp[1600];              \
    N12 = wp[1664]; N13 = wp[1728];                                            \
    MAC(C0) MAC(C1) MAC(C2) MAC(C3) MAC(C4) MAC(C5) MAC(C6)                    \
    MAC(C7) MAC(C8) MAC(C9) MAC(C10) MAC(C11) MAC(C12) MAC(C13)                \
    RENORM                                                                     \
    wp += 896;                                                                 \
  }

  // Groups 0..13: words 0..195 consumed, prefetch through word 209 —
  // all pairs <= 229 (first-half writers only).
  #pragma clang loop unroll(disable)
  for (int it = 0; it < 7; ++it) {
    GROUP(c0,c1,c2,c3,c4,c5,c6,c7,c8,c9,c10,c11,c12,c13,
          n0,n1,n2,n3,n4,n5,n6,n7,n8,n9,n10,n11,n12,n13)
    GROUP(n0,n1,n2,n3,n4,n5,n6,n7,n8,n9,n10,n11,n12,n13,
          c0,c1,c2,c3,c4,c5,c6,c7,c8,c9,c10,c11,c12,c13)
  }
  while (vcnt[1] < 8u) { }   // remaining pairs ready (expected ~0 wait)
  // Groups 14..35 + tail.
  #pragma clang loop unroll(disable)
  for (int it = 0; it < 11; ++it) {
    GROUP(c0,c1,c2,c3,c4,c5,c6,c7,c8,c9,c10,c11,c12,c13,
          n0,n1,n2,n3,n4,n5,n6,n7,n8,n9,n10,n11,n12,n13)
    GROUP(n0,n1,n2,n3,n4,n5,n6,n7,n8,n9,n10,n11,n12,n13,
          c0,c1,c2,c3,c4,c5,c6,c7,c8,c9,c10,c11,c12,c13)
  }
  // tail: words 504..510
  MAC(c0) MAC(c1) MAC(c2) MAC(c3) MAC(c4) MAC(c5) MAC(c6)

#undef GROUP
#undef RENORM
#undef MAC

  // R[511,511] on lane 63; stored E = true * 2^S.
  if (l == 63) {
    ws[k] = -K2 * (__builtin_log2f(E1) - (float)S);
  }
}

__global__ void softdtw_combine_kernel(const float* __restrict__ ws,
                                       float* __restrict__ out) {
  int b = threadIdx.x;
  if (b < NB) out[b] = ws[b] - 0.5f * (ws[NB + b] + ws[2 * NB + b]);
}

extern "C" void kernel_launch(void* const* d_in, const int* in_sizes, int n_in,
                              void* d_out, int out_size, void* d_ws, size_t ws_size,
                              hipStream_t stream) {
  const float* x = (const float*)d_in[0];
  const float* y = (const float*)d_in[1];
  float* ws = (float*)d_ws;
  float* out = (float*)d_out;
  // >64KB dynamic LDS opt-in (not a stream op; capture-safe, idempotent).
  hipFuncSetAttribute((const void*)softdtw_fused,
                      hipFuncAttributeMaxDynamicSharedMemorySize, LDS_BYTES);
  softdtw_fused<<<3 * NB, 1024, LDS_BYTES, stream>>>(x, y, ws);
  softdtw_combine_kernel<<<1, 64, 0, stream>>>(ws, out);
}

// Round 21
// 26.921 us; speedup vs baseline: 1.3676x; 1.0682x over previous
//
#include <hip/hip_runtime.h>

static constexpr int NSEQ = 512;
static constexpr int NB = 32;
static constexpr int LDS_BYTES = 140288;  // 131072 dm + 4096 A2 + 5120 B2pad

typedef _Float16 h2v __attribute__((ext_vector_type(2)));

// lane l <- lane (l-1)&63 : DPP wave rotate-right-by-1 (verified R5-R20).
// Must execute at full exec.
__device__ __forceinline__ float rotup1f(float v) {
  return __int_as_float(__builtin_amdgcn_update_dpp(
      0, __float_as_int(v), 0x13C, 0xf, 0xf, false));
}
__device__ __forceinline__ int rlanei(int v, int idx) {
  return __builtin_amdgcn_readlane(v, idx);
}
__device__ __forceinline__ h2v BCH(unsigned v) { return __builtin_bit_cast(h2v, v); }
__device__ __forceinline__ unsigned packh2s(float a, float b) {
  h2v v; v[0] = (_Float16)a; v[1] = (_Float16)b;
  return __builtin_bit_cast(unsigned, v);
}
#if __has_builtin(__builtin_amdgcn_fdot2)
#define DOT2(a, b, c) __builtin_amdgcn_fdot2((a), (b), (c), false)
#else
__device__ __forceinline__ float dot2f(h2v a, h2v b, float c) {
  return c + (float)a[0] * (float)b[0] + (float)a[1] * (float)b[1];
}
#define DOT2(a, b, c) dot2f((a), (b), (c))
#endif
// v_cvt_pk_bf16_f32: d = {hi: bf16(s1), lo: bf16(s0)}
__device__ __forceinline__ unsigned cvtpk_bf16(float lo, float hi) {
  unsigned r;
  asm("v_cvt_pk_bf16_f32 %0, %1, %2" : "=v"(r) : "v"(lo), "v"(hi));
  return r;
}

// R21 = R20 (verified 28.8us) + two cuts:
//  (A) dhi uses the packed word DIRECTLY as f32 (no AND): low 16 bits are a
//      <=2^-8 relative mantissa perturbation (same order as bf16 rounding).
//      Boundary words (active-lo/inactive-hi) give dhi~2^-133*garbage ->
//      E~2^-71, >=131 bits below the renormed 2^60 max -> absorbed exactly.
//      All-inactive words are fully zero -> exact 0 preserved.
//  (B) 3-level start gating: writers of pair p have rows [p-24,p+26], so
//      bi<=1 (4 waves) covers pairs <=101 -> gate1 opens groups 0..5
//      (prefetch<=97); bi<=3 covers <=229 -> gate2 opens 6..13 (<=209);
//      gate3 (all 16) opens 14..35+tail. DP starts ~3x earlier than R20.
__global__ __launch_bounds__(1024) void softdtw_fused(
    const float* __restrict__ x, const float* __restrict__ y,
    float* __restrict__ ws)
{
  extern __shared__ unsigned char lds_raw[];
  unsigned* dmp = (unsigned*)lds_raw;                 // [512][64] u32 (row 511 scratch)
  uint2* A2  = (uint2*)(lds_raw + 131072);            // [512] f16x4
  uint2* B2p = (uint2*)(lds_raw + 135168);            // [640]; b[j] at index 64+j
  unsigned* cnt = (unsigned*)(lds_raw + 135168 + 96); // B2p[12..13]: 3 gate counters
                                                      // (B2p data reads start at idx 14)

  const int k = blockIdx.x;
  const int batch = k & (NB - 1);
  const int type = k >> 5;
  const float4* Aq = (const float4*)((type == 2 ? y : x) + (size_t)batch * NSEQ * 4);
  const float4* Bq = (const float4*)((type == 1 ? x : y) + (size_t)batch * NSEQ * 4);

  const int tid = threadIdx.x;
  const int l = tid & 63;
  const float SK1 = 0.8493216783f;      // sqrt(1/(2 ln2)); inputs prescaled
  const float K2 = 1.386294361119891f;  // gamma*ln2

  // ---- staging: zero FULL dm region; prescaled f16 a,b; inf pads; counters ----
  {
    uint4* z = (uint4*)lds_raw;         // 8192 uint4 = 131072 B
    #pragma unroll
    for (int q = 0; q < 8; ++q) z[tid + q * 1024] = make_uint4(0u, 0u, 0u, 0u);
    int idx = tid & 511;
    const float4* src = (tid < 512) ? Aq : Bq;
    float4 v = src[idx];
    unsigned w01 = packh2s(v.x * SK1, v.y * SK1);
    unsigned w23 = packh2s(v.z * SK1, v.w * SK1);
    if (tid < 512) A2[idx] = make_uint2(w01, w23);
    else           B2p[64 + idx] = make_uint2(w01, w23);
    if (tid < 64) {
      // indices 12,13 double as gate counters (B2p data reads start at 14)
      B2p[tid] = (tid == 12 || tid == 13) ? make_uint2(0u, 0u)
                                          : make_uint2(0x7C007C00u, 0x7C007C00u);
    } else if (tid < 128) {
      B2p[512 + tid] = make_uint2(0x7C007C00u, 0x7C007C00u);
    }
  }
  __syncthreads();   // the ONLY workgroup barrier

  // ---- stage 1 (i-major, R17-verified): wave (bi,h); i = 64*bi + l ----
  {
    const int wv = tid >> 6;
    const int bi = wv >> 1;
    const int h  = wv & 1;
    const int i  = bi * 64 + l;
    uint2 aw = A2[i];
    h2v a01 = BCH(aw.x), a23 = BCH(aw.y);

    if (h == 0) {
      uint2 bw = B2p[64 + i - 50];            // j = i-50
      h2v d01 = a01 - BCH(bw.x), d23 = a23 - BCH(bw.y);
      float dvv = DOT2(d01, d01, DOT2(d23, d23, 0.0f));
      unsigned w = cvtpk_bf16(0.0f, __builtin_exp2f(-dvv));
      unsigned p = (unsigned)(i - 26);
      if (p > 510u) p = 511u;                 // scratch row (never read)
      dmp[p * 64 + l] = w;
    }
    const int q0 = h ? 0 : -25;
    #pragma unroll 5
    for (int n = 0; n < 25; ++n) {
      int q = q0 + n;
      const uint2* bp = &B2p[64 + i + 2 * q + 1];
      uint2 blo = bp[0];
      uint2 bhi = bp[1];
      h2v e01 = a01 - BCH(blo.x), e23 = a23 - BCH(blo.y);
      float dvl = DOT2(e01, e01, DOT2(e23, e23, 0.0f));
      h2v f01 = a01 - BCH(bhi.x), f23 = a23 - BCH(bhi.y);
      float dvh = DOT2(f01, f01, DOT2(f23, f23, 0.0f));
      unsigned w = cvtpk_bf16(__builtin_exp2f(-dvl), __builtin_exp2f(-dvh));
      unsigned p = (unsigned)(i + q);
      if (p > 510u) p = 511u;
      dmp[p * 64 + l] = w;
    }
    // progress gates: level 0 = bi<=1 (4 waves, pairs<=101),
    // level 1 = bi in {2,3} (4 waves, pairs<=229), level 2 = rest (8 waves).
    // DS queue is in-order per wave => the add is visible only after this
    // wave's dm stores.
    if (l == 0) {
      int level = (bi <= 1) ? 0 : (bi <= 3) ? 1 : 2;
      atomicAdd(&cnt[level], 1u);
    }
  }
  if (tid >= 64) return;

  volatile unsigned* vcnt = (volatile unsigned*)cnt;
  while (vcnt[0] < 4u) { }   // pairs 0..101 ready

  // ---- stage 2: single-wave DP, rotated state (R17-verified) ----
  const unsigned* wp = dmp + l;
  unsigned c0 = wp[0],   c1 = wp[64],  c2 = wp[128], c3 = wp[192],
           c4 = wp[256], c5 = wp[320], c6 = wp[384], c7 = wp[448],
           c8 = wp[512], c9 = wp[576], c10 = wp[640], c11 = wp[704],
           c12 = wp[768], c13 = wp[832];
  unsigned n0, n1, n2, n3, n4, n5, n6, n7, n8, n9, n10, n11, n12, n13;
  int S = 0;

  float E1, r1, r2 = 0.0f;
  {
    uint2 aw = A2[0];
    uint2 bw = B2p[64];
    h2v d01 = BCH(aw.x) - BCH(bw.x);
    h2v d23 = BCH(aw.y) - BCH(bw.y);
    float dv00 = DOT2(d01, d01, DOT2(d23, d23, 0.0f));
    E1 = (l == 0) ? __builtin_exp2f(-dv00) : 0.0f;
  }
  r1 = rotup1f(E1);

#define MAC(W)                                                                 \
  {                                                                            \
    float dlo_ = __int_as_float((W) << 16);                                    \
    float dhi_ = __int_as_float(W);   /* low 16 bits: harmless mantissa */     \
    float sA_ = E1 + r1; sA_ += r2;                                            \
    float eA_ = sA_ * dlo_;                                                    \
    float rA_ = rotup1f(eA_);                                                  \
    float sB_ = eA_ + rA_; sB_ += r1;                                          \
    float eB_ = sB_ * dhi_;                                                    \
    float rB_ = rotup1f(eB_);                                                  \
    E1 = eB_; r2 = rA_; r1 = rB_;                                              \
  }
#define RENORM                                                                 \
  {                                                                            \
    float mx_ = fmaxf(E1, r2);                                                 \
    mx_ = fmaxf(mx_, __int_as_float(__builtin_amdgcn_update_dpp(               \
        0, __float_as_int(mx_), 0x111, 0xf, 0xf, false)));                     \
    mx_ = fmaxf(mx_, __int_as_float(__builtin_amdgcn_update_dpp(               \
        0, __float_as_int(mx_), 0x112, 0xf, 0xf, false)));                     \
    mx_ = fmaxf(mx_, __int_as_float(__builtin_amdgcn_update_dpp(               \
        0, __float_as_int(mx_), 0x114, 0xf, 0xf, false)));                     \
    mx_ = fmaxf(mx_, __int_as_float(__builtin_amdgcn_update_dpp(               \
        0, __float_as_int(mx_), 0x118, 0xf, 0xf, false)));                     \
    mx_ = fmaxf(mx_, __int_as_float(__builtin_amdgcn_update_dpp(               \
        0, __float_as_int(mx_), 0x142, 0xf, 0xf, false)));                     \
    mx_ = fmaxf(mx_, __int_as_float(__builtin_amdgcn_update_dpp(               \
        0, __float_as_int(mx_), 0x143, 0xf, 0xf, false)));                     \
    int c_ = 187 - ((__float_as_int(mx_) >> 23) & 0xFF);                       \
    c_ = rlanei(c_, 63);                                                       \
    E1 = __builtin_ldexpf(E1, c_);                                             \
    r1 = __builtin_ldexpf(r1, c_);                                             \
    r2 = __builtin_ldexpf(r2, c_);                                             \
    S += c_;                                                                   \
  }
#define GROUP(C0,C1,C2,C3,C4,C5,C6,C7,C8,C9,C10,C11,C12,C13,                   \
              N0,N1,N2,N3,N4,N5,N6,N7,N8,N9,N10,N11,N12,N13)                   \
  {                                                                            \
    N0 = wp[896];  N1 = wp[960];  N2 = wp[1024]; N3 = wp[1088];                \
    N4 = wp[1152]; N5 = wp[1216]; N6 = wp[1280]; N7 = wp[1344];                \
    N8 = wp[1408]; N9 = wp[1472]; N10 = wp[1536]; N11 = wp[1600];              \
    N12 = wp[1664]; N13 = wp[1728];                                            \
    MAC(C0) MAC(C1) MAC(C2) MAC(C3) MAC(C4) MAC(C5) MAC(C6)                    \
    MAC(C7) MAC(C8) MAC(C9) MAC(C10) MAC(C11) MAC(C12) MAC(C13)                \
    RENORM                                                                     \
    wp += 896;                                                                 \
  }

  // Groups 0..5: consume words 0..83, prefetch through word 97 (pairs<=101 ok).
  #pragma clang loop unroll(disable)
  for (int it = 0; it < 3; ++it) {
    GROUP(c0,c1,c2,c3,c4,c5,c6,c7,c8,c9,c10,c11,c12,c13,
          n0,n1,n2,n3,n4,n5,n6,n7,n8,n9,n10,n11,n12,n13)
    GROUP(n0,n1,n2,n3,n4,n5,n6,n7,n8,n9,n10,n11,n12,n13,
          c0,c1,c2,c3,c4,c5,c6,c7,c8,c9,c10,c11,c12,c13)
  }
  while (vcnt[1] < 4u) { }   // pairs 0..229 ready
  // Groups 6..13: prefetch through word 209 (pairs<=229 ok).
  #pragma clang loop unroll(disable)
  for (int it = 0; it < 4; ++it) {
    GROUP(c0,c1,c2,c3,c4,c5,c6,c7,c8,c9,c10,c11,c12,c13,
          n0,n1,n2,n3,n4,n5,n6,n7,n8,n9,n10,n11,n12,n13)
    GROUP(n0,n1,n2,n3,n4,n5,n6,n7,n8,n9,n10,n11,n12,n13,
          c0,c1,c2,c3,c4,c5,c6,c7,c8,c9,c10,c11,c12,c13)
  }
  while (vcnt[2] < 8u) { }   // all pairs ready
  // Groups 14..35 + tail.
  #pragma clang loop unroll(disable)
  for (int it = 0; it < 11; ++it) {
    GROUP(c0,c1,c2,c3,c4,c5,c6,c7,c8,c9,c10,c11,c12,c13,
          n0,n1,n2,n3,n4,n5,n6,n7,n8,n9,n10,n11,n12,n13)
    GROUP(n0,n1,n2,n3,n4,n5,n6,n7,n8,n9,n10,n11,n12,n13,
          c0,c1,c2,c3,c4,c5,c6,c7,c8,c9,c10,c11,c12,c13)
  }
  // tail: words 504..510
  MAC(c0) MAC(c1) MAC(c2) MAC(c3) MAC(c4) MAC(c5) MAC(c6)

#undef GROUP
#undef RENORM
#undef MAC

  // R[511,511] on lane 63; stored E = true * 2^S.
  if (l == 63) {
    ws[k] = -K2 * (__builtin_log2f(E1) - (float)S);
  }
}

__global__ void softdtw_combine_kernel(const float* __restrict__ ws,
                                       float* __restrict__ out) {
  int b = threadIdx.x;
  if (b < NB) out[b] = ws[b] - 0.5f * (ws[NB + b] + ws[2 * NB + b]);
}

extern "C" void kernel_launch(void* const* d_in, const int* in_sizes, int n_in,
                              void* d_out, int out_size, void* d_ws, size_t ws_size,
                              hipStream_t stream) {
  const float* x = (const float*)d_in[0];
  const float* y = (const float*)d_in[1];
  float* ws = (float*)d_ws;
  float* out = (float*)d_out;
  // >64KB dynamic LDS opt-in (not a stream op; capture-safe, idempotent).
  hipFuncSetAttribute((const void*)softdtw_fused,
                      hipFuncAttributeMaxDynamicSharedMemorySize, LDS_BYTES);
  softdtw_fused<<<3 * NB, 1024, LDS_BYTES, stream>>>(x, y, ws);
  softdtw_combine_kernel<<<1, 64, 0, stream>>>(ws, out);
}